// Round 7
// baseline (503.825 us; speedup 1.0000x reference)
//
#include <hip/hip_runtime.h>
#include <hip/hip_cooperative_groups.h>
#include <math.h>

namespace cg = cooperative_groups;

#define T_TOTAL   131072
#define POSE_FLTS (131072 * 216)       // 28311552
#define BT        64                   // timesteps per scan unit
#define NU        (T_TOTAL / BT)       // 2048 units
#define NPB       1792                 // persistent blocks (7/CU * 256 CU)
#define F4PB      (BT * 54)            // 3456 float4 per unit slice
#define TILE_W    65                   // 64 ts + boundary column
#define TILE_F    72                   // compact floats per ts
#define SCR       (TILE_F * TILE_W)    // scratch offset (boundary feet / wtot)
#define FLOOR_YC  (-0.93f)
#define GRAV_Y    (-0.0018f)
#define NEG_INF   (-INFINITY)

typedef float floatx4 __attribute__((ext_vector_type(4)));

// ---------------- small math helpers (constant-indexed after inlining) ------

__device__ __forceinline__ void mat3mul(const float* A, const float* B, float* C) {
#pragma unroll
    for (int r = 0; r < 3; ++r) {
#pragma unroll
        for (int c = 0; c < 3; ++c) {
            C[r * 3 + c] = fmaf(A[r * 3 + 2], B[6 + c],
                           fmaf(A[r * 3 + 1], B[3 + c],
                                A[r * 3 + 0] * B[c]));
        }
    }
}

__device__ __forceinline__ void mva(const float* R, const float* b,
                                    const float* pin, float* pout) {
#pragma unroll
    for (int r = 0; r < 3; ++r) {
        pout[r] = pin[r] + fmaf(R[r * 3 + 2], b[2],
                            fmaf(R[r * 3 + 1], b[1], R[r * 3 + 0] * b[0]));
    }
}

__device__ __forceinline__ float sel_foot(const float f[12], int idx, int c) {
    float r = f[0 + c];
    r = (idx == 1) ? f[3 + c] : r;
    r = (idx == 2) ? f[6 + c] : r;
    r = (idx == 3) ? f[9 + c] : r;
    return r;
}

// shared FK core: joints at compact float offsets M0..M6
__device__ __forceinline__ void fk_core(const float* Pl, int o1, int o2, int o3,
                                        int o4, int o5, int o6,
                                        const float* __restrict__ bone,
                                        float feet[12], float* fmin) {
    const float* M0 = Pl + 0;
    const float* M1 = Pl + o1;
    const float* M2 = Pl + o2;
    const float* M3 = Pl + o3;
    const float* M4 = Pl + o4;
    const float* M5 = Pl + o5;
    const float* M6 = Pl + o6;

    float R1[9], R2[9], R3[9], R4[9], R5[9], R6[9];
    mat3mul(M0, M1, R1);
    mat3mul(M0, M2, R2);
    mat3mul(R1, M3, R3);
    mat3mul(R2, M4, R4);
    mat3mul(R3, M5, R5);
    mat3mul(R4, M6, R6);

    float p0[3] = {bone[0], bone[1], bone[2]};
    float p1[3], p2[3], p3[3], p4a[3], p5[3], p6[3], p7[3], p8[3];
    mva(M0, bone + 3,  p0, p1);
    mva(M0, bone + 6,  p0, p2);
    mva(R1, bone + 9,  p1, p3);
    mva(R2, bone + 12, p2, p4a);
    mva(R3, bone + 15, p3, p5);
    mva(R4, bone + 18, p4a, p6);
    mva(R5, bone + 21, p5, p7);
    mva(R6, bone + 24, p6, p8);

    // FEET = [7,5,8,6]
    feet[0] = p7[0]; feet[1]  = p7[1]; feet[2]  = p7[2];
    feet[3] = p5[0]; feet[4]  = p5[1]; feet[5]  = p5[2];
    feet[6] = p8[0]; feet[7]  = p8[1]; feet[8]  = p8[2];
    feet[9] = p6[0]; feet[10] = p6[1]; feet[11] = p6[2];
    *fmin = fminf(fminf(p5[1], p6[1]), fminf(p7[1], p8[1]));
}

// FK from global pose (orig layout, float4 loads) — fallback path
__device__ __forceinline__ void fk_feet_ptr(const float* __restrict__ P,
                                            const float* __restrict__ bone,
                                            float feet[12], float* fmin) {
    float Pl[84];
    const floatx4* p4 = (const floatx4*)P;
#pragma unroll
    for (int i = 0; i < 7; ++i) { floatx4 q = p4[i]; Pl[4*i]=q.x; Pl[4*i+1]=q.y; Pl[4*i+2]=q.z; Pl[4*i+3]=q.w; }
#pragma unroll
    for (int i = 9; i < 14; ++i) { floatx4 q = p4[i]; Pl[4*i]=q.x; Pl[4*i+1]=q.y; Pl[4*i+2]=q.z; Pl[4*i+3]=q.w; }
#pragma unroll
    for (int i = 15; i < 21; ++i) { floatx4 q = p4[i]; Pl[4*i]=q.x; Pl[4*i+1]=q.y; Pl[4*i+2]=q.z; Pl[4*i+3]=q.w; }
    fk_core(Pl, 9, 18, 36, 45, 63, 72, bone, feet, fmin);
}

// FK from transposed compact LDS tile: float f of column c at tile[f*TILE_W+c]
__device__ __forceinline__ void fk_feet_col(const float* __restrict__ tile, int col,
                                            const float* __restrict__ bone,
                                            float feet[12], float* fmin) {
    float Pl[TILE_F];
#pragma unroll
    for (int f = 0; f < TILE_F; ++f) Pl[f] = tile[f * TILE_W + col];
    // compact offsets: M0=0 M1=9 M2=18 M3=28 M4=37 M5=51 M6=60
    fk_core(Pl, 9, 18, 28, 37, 51, 60, bone, feet, fmin);
}

// inclusive wave scan (non-commutative compose, earlier = lower lane)
__device__ __forceinline__ void wave_incl_scan(float& Sx, float& Sz,
                                               float& A, float& B, int lane) {
#pragma unroll
    for (int off = 1; off < 64; off <<= 1) {
        float ox = __shfl_up(Sx, off, 64);
        float oz = __shfl_up(Sz, off, 64);
        float oA = __shfl_up(A, off, 64);
        float oB = __shfl_up(B, off, 64);
        if (lane >= off) {
            Sx += ox;
            Sz += oz;
            B = fmaxf(oB + A, B);  // B uses pre-update A
            A = oA + A;
        }
    }
}

// scatter one copied float4 into the transposed compact tile (if needed)
__device__ __forceinline__ void extract_tile(float* __restrict__ tile, int idx, floatx4 q) {
    int tsl = idx / 54;
    int w   = idx - tsl * 54;
    int base = -1;
    if (w <= 6)                 base = 4 * w;        // floats 0..27
    else if (w >= 9 && w <= 13) base = 4 * w - 8;    // floats 36..55 -> 28..47
    else if (w >= 15 && w <= 20) base = 4 * w - 12;  // floats 60..83 -> 48..71
    if (base >= 0) {
        tile[(base + 0) * TILE_W + tsl] = q.x;
        tile[(base + 1) * TILE_W + tsl] = q.y;
        tile[(base + 2) * TILE_W + tsl] = q.z;
        tile[(base + 3) * TILE_W + tsl] = q.w;
    }
}

// ---------------- cooperative fused kernel -----------------------------------

// one unit: copy 64-ts slice + extract to tile + FK + velocity + wave scan.
// returns inclusive scan state for tid<64.
__device__ __forceinline__ void unit_pass(const float* __restrict__ pose,
                                          const float* __restrict__ bone,
                                          const int* __restrict__ index,
                                          floatx4* __restrict__ outPose4,
                                          float4* __restrict__ wsAgg,
                                          float* __restrict__ tile,
                                          int u, int tid,
                                          float& ix, float& iz, float& iA, float& iB) {
    const floatx4* __restrict__ src = (const floatx4*)pose + (size_t)u * F4PB;
    floatx4*       __restrict__ dst = outPose4              + (size_t)u * F4PB;

    floatx4 r[7];
#pragma unroll
    for (int j = 0; j < 7; ++j) r[j] = src[j * 256 + tid];
#pragma unroll
    for (int j = 0; j < 7; ++j) {
        int idx = j * 256 + tid;
        __builtin_nontemporal_store(r[j], &dst[idx]);
        extract_tile(tile, idx, r[j]);
    }
#pragma unroll
    for (int j = 0; j < 6; ++j) r[j] = src[(7 + j) * 256 + tid];
#pragma unroll
    for (int j = 0; j < 6; ++j) {
        int idx = (7 + j) * 256 + tid;
        __builtin_nontemporal_store(r[j], &dst[idx]);
        extract_tile(tile, idx, r[j]);
    }
    if (tid < 128) {
        int idx = 13 * 256 + tid;
        floatx4 q = src[idx];
        __builtin_nontemporal_store(q, &dst[idx]);
        extract_tile(tile, idx, q);
    } else if (u > 0 && tid < 128 + 18) {
        // boundary timestep u*BT-1 -> tile column 64
        int k = tid - 128;
        int o = k + (k >= 7 ? 2 : 0) + (k >= 12 ? 1 : 0);   // orig float4 idx
        floatx4 q = *(const floatx4*)(pose + ((size_t)u * BT - 1) * 216 + o * 4);
#pragma unroll
        for (int i = 0; i < 4; ++i) tile[(4 * k + i) * TILE_W + 64] = q[i];
    }
    __syncthreads();

    float feet[12], fmin = 0.f;
    if (tid < 64) {
        fk_feet_col(tile, tid, bone, feet, &fmin);
    } else if (tid == 64 && u > 0) {
        float f2[12], m2;
        fk_feet_col(tile, 64, bone, f2, &m2);
#pragma unroll
        for (int k = 0; k < 12; ++k) tile[SCR + k] = f2[k];
    }
    __syncthreads();

    if (tid < 64) {
        int lane = tid;
        int t = u * BT + lane;

        float fp[12];
#pragma unroll
        for (int k = 0; k < 12; ++k) fp[k] = __shfl_up(feet[k], 1, 64);
        if (lane == 0 && u > 0) {
#pragma unroll
            for (int k = 0; k < 12; ++k) fp[k] = tile[SCR + k];
        }

        float vx, vy, vz;
        if (t == 0) {
            vx = 0.f; vy = GRAV_Y; vz = 0.f;
        } else {
            int idx = index[t];
            vx = sel_foot(fp, idx, 0) - sel_foot(feet, idx, 0);
            vy = GRAV_Y + sel_foot(fp, idx, 1) - sel_foot(feet, idx, 1);
            vz = sel_foot(fp, idx, 2) - sel_foot(feet, idx, 2);
        }
        ix = vx; iz = vz; iA = vy; iB = FLOOR_YC - fmin;
        wave_incl_scan(ix, iz, iA, iB, lane);
        if (lane == 63) wsAgg[u] = make_float4(ix, iz, iA, iB);
    }
    __syncthreads();   // tile safe for reuse
}

__global__ __launch_bounds__(256, 8) void k_all(const float* __restrict__ pose,
                                                const float* __restrict__ bone,
                                                const int* __restrict__ index,
                                                floatx4* __restrict__ outPose4,
                                                float4* __restrict__ wsAgg,
                                                float4* __restrict__ wsIn,
                                                float* __restrict__ trans) {
    __shared__ __align__(16) float tile[SCR + 16];
    int tid = threadIdx.x, b = blockIdx.x;

    float ix0 = 0.f, iz0 = 0.f, iA0 = 0.f, iB0 = NEG_INF;
    float ix1 = 0.f, iz1 = 0.f, iA1 = 0.f, iB1 = NEG_INF;

    unit_pass(pose, bone, index, outPose4, wsAgg, tile, b, tid, ix0, iz0, iA0, iB0);
    bool two = (b < NU - NPB);                        // first 256 blocks take a 2nd unit
    if (two)
        unit_pass(pose, bone, index, outPose4, wsAgg, tile, b + NPB, tid, ix1, iz1, iA1, iB1);

    cg::this_grid().sync();

    // ---- phase2: block 0 scans the 2048 unit aggregates -------------------
    if (b == 0) {
        float4 a[8];
#pragma unroll
        for (int k = 0; k < 8; ++k) a[k] = wsAgg[tid * 8 + k];
        float cx = a[0].x, cz = a[0].y, ca = a[0].z, cb = a[0].w;
#pragma unroll
        for (int k = 1; k < 8; ++k) {
            cb = fmaxf(cb + a[k].z, a[k].w);
            ca += a[k].z;
            cx += a[k].x; cz += a[k].y;
        }
        int lane = tid & 63, wv = tid >> 6;
        float sx = cx, sz = cz, sa = ca, sb = cb;
        wave_incl_scan(sx, sz, sa, sb, lane);
        float4* wtot = (float4*)tile;
        if (lane == 63) wtot[wv] = make_float4(sx, sz, sa, sb);
        __syncthreads();

        float ex = __shfl_up(sx, 1, 64);
        float ez = __shfl_up(sz, 1, 64);
        float eA = __shfl_up(sa, 1, 64);
        float eB = __shfl_up(sb, 1, 64);
        if (lane == 0) { ex = 0.f; ez = 0.f; eA = 0.f; eB = NEG_INF; }

        float wx = 0.f, wz = 0.f, wA = 0.f, wB = NEG_INF;
        for (int w = 0; w < wv; ++w) {
            float4 c = wtot[w];
            wx += c.x; wz += c.y;
            wB = fmaxf(wB + c.z, c.w);
            wA += c.z;
        }
        float tx = wx + ex, tz = wz + ez;
        float tB = fmaxf(wB + eA, eB);
        float tA = wA + eA;
#pragma unroll
        for (int k = 0; k < 8; ++k) {
            wsIn[tid * 8 + k] = make_float4(tx, tz, fmaxf(tA, tB), 0.f);
            tB = fmaxf(tB + a[k].z, a[k].w);
            tA += a[k].z;
            tx += a[k].x; tz += a[k].y;
        }
    }

    cg::this_grid().sync();

    // ---- apply: write trans from registers --------------------------------
    if (tid < 64) {
        float4 p = wsIn[b];
        size_t t = (size_t)b * BT + tid;
        trans[t * 3 + 0] = p.x + ix0;
        trans[t * 3 + 1] = fmaxf(p.z + iA0, iB0);
        trans[t * 3 + 2] = p.y + iz0;
        if (two) {
            float4 q = wsIn[b + NPB];
            size_t t1 = (size_t)(b + NPB) * BT + tid;
            trans[t1 * 3 + 0] = q.x + ix1;
            trans[t1 * 3 + 1] = fmaxf(q.z + iA1, iB1);
            trans[t1 * 3 + 2] = q.y + iz1;
        }
    }
}

// ---------------- fallback 3-kernel path (round-6, proven) ------------------

__global__ __launch_bounds__(256) void k_main(const float* __restrict__ pose,
                                              const float* __restrict__ bone,
                                              const int* __restrict__ index,
                                              floatx4* __restrict__ outPose4,
                                              float4* __restrict__ vws,
                                              float4* __restrict__ wsAgg) {
    __shared__ __align__(16) float tile[SCR + 16];
    int tid = threadIdx.x, b = blockIdx.x;
    float ix, iz, iA, iB;
    unit_pass(pose, bone, index, outPose4, wsAgg, tile, b, tid, ix, iz, iA, iB);
    if (tid < 64) {
        // recover per-element operand for phase3: store exclusive-applied later;
        // simplest: store inclusive scan state per element
        vws[(size_t)b * BT + tid] = make_float4(ix, iz, iA, iB);
    }
}

__global__ __launch_bounds__(1024) void k_phase2(const float4* __restrict__ wsAgg,
                                                 float4* __restrict__ wsIn) {
    __shared__ float sx[1024], sz[1024], sa[1024], sb[1024];
    int tid = threadIdx.x;

    float4 a0 = wsAgg[2 * tid];
    float4 a1 = wsAgg[2 * tid + 1];
    float cx = a0.x + a1.x;
    float cz = a0.y + a1.y;
    float cb = fmaxf(a0.w + a1.z, a1.w);
    float ca = a0.z + a1.z;
    sx[tid] = cx; sz[tid] = cz; sa[tid] = ca; sb[tid] = cb;
    __syncthreads();

    for (int off = 1; off < 1024; off <<= 1) {
        float px = 0.f, pz = 0.f, pa = 0.f, pb = NEG_INF;
        bool h = (tid >= off);
        if (h) { px = sx[tid - off]; pz = sz[tid - off]; pa = sa[tid - off]; pb = sb[tid - off]; }
        __syncthreads();
        if (h) {
            float qa = sa[tid], qb = sb[tid];
            sx[tid] = px + sx[tid];
            sz[tid] = pz + sz[tid];
            sb[tid] = fmaxf(pb + qa, qb);
            sa[tid] = pa + qa;
        }
        __syncthreads();
    }

    float ex = 0.f, ez = 0.f, ea = 0.f, eb = NEG_INF;
    if (tid > 0) { ex = sx[tid - 1]; ez = sz[tid - 1]; ea = sa[tid - 1]; eb = sb[tid - 1]; }

    wsIn[2 * tid] = make_float4(ex, ez, fmaxf(ea, eb), 0.f);

    float fx = ex + a0.x;
    float fz = ez + a0.y;
    float fb = fmaxf(eb + a0.z, a0.w);
    float fa = ea + a0.z;
    wsIn[2 * tid + 1] = make_float4(fx, fz, fmaxf(fa, fb), 0.f);
}

__global__ __launch_bounds__(256) void k_phase3(const float4* __restrict__ vws,
                                                const float4* __restrict__ wsIn,
                                                float* __restrict__ trans) {
    int tid = threadIdx.x, bk = blockIdx.x;
    int lane = tid & 63, wv = tid >> 6;
    int u = bk * 4 + wv;
    size_t t = (size_t)u * 64 + lane;

    float4 v = vws[t];           // inclusive scan state (already scanned in k_main)
    float4 bin = wsIn[u];
    trans[t * 3 + 0] = bin.x + v.x;
    trans[t * 3 + 1] = fmaxf(bin.z + v.z, v.w);
    trans[t * 3 + 2] = bin.y + v.y;
}

// ---------------- launch -----------------------------------------------------

extern "C" void kernel_launch(void* const* d_in, const int* in_sizes, int n_in,
                              void* d_out, int out_size, void* d_ws, size_t ws_size,
                              hipStream_t stream) {
    const float* pose  = (const float*)d_in[0];
    const float* bone  = (const float*)d_in[1];
    const int*   index = (const int*)d_in[2];
    float* out   = (float*)d_out;
    float* trans = out + POSE_FLTS;

    float4* vws   = (float4*)d_ws;         // T entries (fallback only)
    float4* wsAgg = vws + T_TOTAL;         // NU entries
    float4* wsIn  = wsAgg + NU;            // NU entries
    floatx4* outP = (floatx4*)out;

    void* args[7] = {(void*)&pose, (void*)&bone, (void*)&index,
                     (void*)&outP, (void*)&wsAgg, (void*)&wsIn, (void*)&trans};
    hipError_t e = hipLaunchCooperativeKernel((void*)k_all, dim3(NPB), dim3(256),
                                              args, 0, stream);
    if (e != hipSuccess) {
        // fallback: proven 3-kernel path
        k_main  <<<NU, 256, 0, stream>>>(pose, bone, index, outP, vws, wsAgg);
        k_phase2<<<1, 1024, 0, stream>>>(wsAgg, wsIn);
        k_phase3<<<NU / 4, 256, 0, stream>>>(vws, wsIn, trans);
    }
}

// Round 8
// 51.740 us; speedup vs baseline: 9.7376x; 9.7376x over previous
//
#include <hip/hip_runtime.h>
#include <math.h>

#define T_TOTAL   131072
#define POSE_FLTS (131072 * 216)       // 28311552
#define BT        64                   // timesteps per scan unit / block
#define NU        (T_TOTAL / BT)       // 2048 units
#define F4PB      (BT * 54)            // 3456 float4 per unit slice
#define TILE_W    65                   // 64 ts + boundary column
#define TILE_F    72                   // compact floats per ts
#define SCR       (TILE_F * TILE_W)    // scratch offset (boundary feet)
#define FLOOR_YC  (-0.93f)
#define GRAV_Y    (-0.0018f)
#define NEG_INF   (-INFINITY)

typedef float floatx4 __attribute__((ext_vector_type(4)));

// ---------------- small math helpers (constant-indexed after inlining) ------

__device__ __forceinline__ void mat3mul(const float* A, const float* B, float* C) {
#pragma unroll
    for (int r = 0; r < 3; ++r) {
#pragma unroll
        for (int c = 0; c < 3; ++c) {
            C[r * 3 + c] = fmaf(A[r * 3 + 2], B[6 + c],
                           fmaf(A[r * 3 + 1], B[3 + c],
                                A[r * 3 + 0] * B[c]));
        }
    }
}

__device__ __forceinline__ void mva(const float* R, const float* b,
                                    const float* pin, float* pout) {
#pragma unroll
    for (int r = 0; r < 3; ++r) {
        pout[r] = pin[r] + fmaf(R[r * 3 + 2], b[2],
                            fmaf(R[r * 3 + 1], b[1], R[r * 3 + 0] * b[0]));
    }
}

__device__ __forceinline__ float sel_foot(const float f[12], int idx, int c) {
    float r = f[0 + c];
    r = (idx == 1) ? f[3 + c] : r;
    r = (idx == 2) ? f[6 + c] : r;
    r = (idx == 3) ? f[9 + c] : r;
    return r;
}

// FK core on a compact 72-float pose (joint offsets 0,9,18,28,37,51,60)
__device__ __forceinline__ void fk_core(const float* Pl,
                                        const float* __restrict__ bone,
                                        float feet[12], float* fmin) {
    const float* M0 = Pl + 0;
    const float* M1 = Pl + 9;
    const float* M2 = Pl + 18;
    const float* M3 = Pl + 28;
    const float* M4 = Pl + 37;
    const float* M5 = Pl + 51;
    const float* M6 = Pl + 60;

    float R1[9], R2[9], R3[9], R4[9], R5[9], R6[9];
    mat3mul(M0, M1, R1);
    mat3mul(M0, M2, R2);
    mat3mul(R1, M3, R3);
    mat3mul(R2, M4, R4);
    mat3mul(R3, M5, R5);
    mat3mul(R4, M6, R6);

    float p0[3] = {bone[0], bone[1], bone[2]};
    float p1[3], p2[3], p3[3], p4a[3], p5[3], p6[3], p7[3], p8[3];
    mva(M0, bone + 3,  p0, p1);
    mva(M0, bone + 6,  p0, p2);
    mva(R1, bone + 9,  p1, p3);
    mva(R2, bone + 12, p2, p4a);
    mva(R3, bone + 15, p3, p5);
    mva(R4, bone + 18, p4a, p6);
    mva(R5, bone + 21, p5, p7);
    mva(R6, bone + 24, p6, p8);

    // FEET = [7,5,8,6]
    feet[0] = p7[0]; feet[1]  = p7[1]; feet[2]  = p7[2];
    feet[3] = p5[0]; feet[4]  = p5[1]; feet[5]  = p5[2];
    feet[6] = p8[0]; feet[7]  = p8[1]; feet[8]  = p8[2];
    feet[9] = p6[0]; feet[10] = p6[1]; feet[11] = p6[2];
    *fmin = fminf(fminf(p5[1], p6[1]), fminf(p7[1], p8[1]));
}

// FK from transposed compact LDS tile: float f of column c at tile[f*TILE_W+c]
// reads: bank = (f*65 + col) mod 32 -> 2 lanes/bank = conflict-free
__device__ __forceinline__ void fk_feet_col(const float* __restrict__ tile, int col,
                                            const float* __restrict__ bone,
                                            float feet[12], float* fmin) {
    float Pl[TILE_F];
#pragma unroll
    for (int f = 0; f < TILE_F; ++f) Pl[f] = tile[f * TILE_W + col];
    fk_core(Pl, bone, feet, fmin);
}

// inclusive wave scan (non-commutative compose, earlier = lower lane)
__device__ __forceinline__ void wave_incl_scan(float& Sx, float& Sz,
                                               float& A, float& B, int lane) {
#pragma unroll
    for (int off = 1; off < 64; off <<= 1) {
        float ox = __shfl_up(Sx, off, 64);
        float oz = __shfl_up(Sz, off, 64);
        float oA = __shfl_up(A, off, 64);
        float oB = __shfl_up(B, off, 64);
        if (lane >= off) {
            Sx += ox;
            Sz += oz;
            B = fmaxf(oB + A, B);  // B uses pre-update A
            A = oA + A;
        }
    }
}

// scatter one copied float4 into the transposed compact tile (if needed)
__device__ __forceinline__ void extract_tile(float* __restrict__ tile, int idx, floatx4 q) {
    int tsl = idx / 54;
    int w   = idx - tsl * 54;
    int base = -1;
    if (w <= 6)                  base = 4 * w;       // floats 0..27
    else if (w >= 9 && w <= 13)  base = 4 * w - 8;   // floats 36..55 -> 28..47
    else if (w >= 15 && w <= 20) base = 4 * w - 12;  // floats 60..83 -> 48..71
    if (base >= 0) {
        tile[(base + 0) * TILE_W + tsl] = q.x;
        tile[(base + 1) * TILE_W + tsl] = q.y;
        tile[(base + 2) * TILE_W + tsl] = q.z;
        tile[(base + 3) * TILE_W + tsl] = q.w;
    }
}

// ---------------- main kernel ------------------------------------------------

__global__ __launch_bounds__(256) void k_main(const float* __restrict__ pose,
                                              const float* __restrict__ bone,
                                              const int* __restrict__ index,
                                              floatx4* __restrict__ outPose4,
                                              float4* __restrict__ vws,
                                              float4* __restrict__ wsAgg) {
    __shared__ __align__(16) float tile[SCR + 16];
    int tid = threadIdx.x, u = blockIdx.x;

    const floatx4* __restrict__ src = (const floatx4*)pose + (size_t)u * F4PB;
    floatx4*       __restrict__ dst = outPose4              + (size_t)u * F4PB;

    // ---- issue ALL loads up front (max memory-level parallelism) ----------
    floatx4 r[14];
#pragma unroll
    for (int j = 0; j < 13; ++j) r[j] = src[j * 256 + tid];
    floatx4 qb;
    bool has14   = (tid < 128);
    bool hasBnd  = (u > 0 && tid >= 128 && tid < 128 + 18);
    if (has14) {
        r[13] = src[13 * 256 + tid];
    } else if (hasBnd) {
        // boundary timestep u*BT-1 (18 needed float4s) -> tile column 64
        int k = tid - 128;
        int o = k + (k >= 7 ? 2 : 0) + (k >= 12 ? 1 : 0);   // orig float4 idx
        qb = *(const floatx4*)(pose + ((size_t)u * BT - 1) * 216 + o * 4);
    }

    // ---- drain: NT store + LDS extract ------------------------------------
#pragma unroll
    for (int j = 0; j < 13; ++j) {
        int idx = j * 256 + tid;
        __builtin_nontemporal_store(r[j], &dst[idx]);
        extract_tile(tile, idx, r[j]);
    }
    if (has14) {
        int idx = 13 * 256 + tid;
        __builtin_nontemporal_store(r[13], &dst[idx]);
        extract_tile(tile, idx, r[13]);
    } else if (hasBnd) {
        int k = tid - 128;
#pragma unroll
        for (int i = 0; i < 4; ++i) tile[(4 * k + i) * TILE_W + 64] = qb[i];
    }
    __syncthreads();

    // ---- FK: wave 0 columns 0..63; wave-1 lane 0 does boundary column -----
    float feet[12], fmin = 0.f;
    if (tid < 64) {
        fk_feet_col(tile, tid, bone, feet, &fmin);
    } else if (tid == 64 && u > 0) {
        float f2[12], m2;
        fk_feet_col(tile, 64, bone, f2, &m2);
#pragma unroll
        for (int k = 0; k < 12; ++k) tile[SCR + k] = f2[k];
    }
    __syncthreads();

    // ---- velocity + inclusive wave scan + aggregate (wave 0 only) ---------
    if (tid < 64) {
        int lane = tid;
        int t = u * BT + lane;

        float fp[12];
#pragma unroll
        for (int k = 0; k < 12; ++k) fp[k] = __shfl_up(feet[k], 1, 64);
        if (lane == 0 && u > 0) {
#pragma unroll
            for (int k = 0; k < 12; ++k) fp[k] = tile[SCR + k];
        }

        float vx, vy, vz;
        if (t == 0) {
            vx = 0.f; vy = GRAV_Y; vz = 0.f;
        } else {
            int idx = index[t];
            vx = sel_foot(fp, idx, 0) - sel_foot(feet, idx, 0);
            vy = GRAV_Y + sel_foot(fp, idx, 1) - sel_foot(feet, idx, 1);
            vz = sel_foot(fp, idx, 2) - sel_foot(feet, idx, 2);
        }
        float ix = vx, iz = vz, iA = vy, iB = FLOOR_YC - fmin;
        wave_incl_scan(ix, iz, iA, iB, lane);

        vws[(size_t)t] = make_float4(ix, iz, iA, iB);   // inclusive state
        if (lane == 63) wsAgg[u] = make_float4(ix, iz, iA, iB);
    }
}

// Scan of 2048 unit aggregates -> per-unit entering state (x, z, root_y).
__global__ __launch_bounds__(1024) void k_phase2(const float4* __restrict__ wsAgg,
                                                 float4* __restrict__ wsIn) {
    __shared__ float sx[1024], sz[1024], sa[1024], sb[1024];
    int tid = threadIdx.x;

    float4 a0 = wsAgg[2 * tid];
    float4 a1 = wsAgg[2 * tid + 1];
    float cx = a0.x + a1.x;
    float cz = a0.y + a1.y;
    float cb = fmaxf(a0.w + a1.z, a1.w);
    float ca = a0.z + a1.z;
    sx[tid] = cx; sz[tid] = cz; sa[tid] = ca; sb[tid] = cb;
    __syncthreads();

    for (int off = 1; off < 1024; off <<= 1) {
        float px = 0.f, pz = 0.f, pa = 0.f, pb = NEG_INF;
        bool h = (tid >= off);
        if (h) { px = sx[tid - off]; pz = sz[tid - off]; pa = sa[tid - off]; pb = sb[tid - off]; }
        __syncthreads();
        if (h) {
            float qa = sa[tid], qb = sb[tid];
            sx[tid] = px + sx[tid];
            sz[tid] = pz + sz[tid];
            sb[tid] = fmaxf(pb + qa, qb);
            sa[tid] = pa + qa;
        }
        __syncthreads();
    }

    float ex = 0.f, ez = 0.f, ea = 0.f, eb = NEG_INF;
    if (tid > 0) { ex = sx[tid - 1]; ez = sz[tid - 1]; ea = sa[tid - 1]; eb = sb[tid - 1]; }

    wsIn[2 * tid] = make_float4(ex, ez, fmaxf(ea, eb), 0.f);

    float fx = ex + a0.x;
    float fz = ez + a0.y;
    float fb = fmaxf(eb + a0.z, a0.w);
    float fa = ea + a0.z;
    wsIn[2 * tid + 1] = make_float4(fx, fz, fmaxf(fa, fb), 0.f);
}

// Final: pure apply — vws already holds the inclusive in-unit scan state.
__global__ __launch_bounds__(256) void k_phase3(const float4* __restrict__ vws,
                                                const float4* __restrict__ wsIn,
                                                float* __restrict__ trans) {
    int tid = threadIdx.x, bk = blockIdx.x;
    int lane = tid & 63, wv = tid >> 6;
    int u = bk * 4 + wv;
    size_t t = (size_t)u * 64 + lane;

    float4 v   = vws[t];
    float4 bin = wsIn[u];
    trans[t * 3 + 0] = bin.x + v.x;
    trans[t * 3 + 1] = fmaxf(bin.z + v.z, v.w);
    trans[t * 3 + 2] = bin.y + v.y;
}

// ---------------- launch -----------------------------------------------------

extern "C" void kernel_launch(void* const* d_in, const int* in_sizes, int n_in,
                              void* d_out, int out_size, void* d_ws, size_t ws_size,
                              hipStream_t stream) {
    const float* pose  = (const float*)d_in[0];
    const float* bone  = (const float*)d_in[1];
    const int*   index = (const int*)d_in[2];
    float* out   = (float*)d_out;
    float* trans = out + POSE_FLTS;

    float4* vws   = (float4*)d_ws;         // T entries (2 MB)
    float4* wsAgg = vws + T_TOTAL;         // NU entries
    float4* wsIn  = wsAgg + NU;            // NU entries

    k_main  <<<NU, 256, 0, stream>>>(pose, bone, index, (floatx4*)out, vws, wsAgg);
    k_phase2<<<1, 1024, 0, stream>>>(wsAgg, wsIn);
    k_phase3<<<NU / 4, 256, 0, stream>>>(vws, wsIn, trans);
}